// Round 4
// baseline (437.713 us; speedup 1.0000x reference)
//
#include <hip/hip_runtime.h>
#include <hip/hip_bf16.h>

#define NN 50000
#define NE 600000
#define D 128

typedef __bf16 bf16x8 __attribute__((ext_vector_type(8)));
typedef __bf16 bf16x4 __attribute__((ext_vector_type(4)));
typedef float f32x4 __attribute__((ext_vector_type(4)));

// ---- helpers -------------------------------------------------------------

// async 16B global->LDS (per-lane global addr, wave-uniform LDS base + lane*16)
static __device__ __forceinline__ void gload_lds16(const void* g, void* l) {
  __builtin_amdgcn_global_load_lds(
      (const __attribute__((address_space(1))) unsigned int*)g,
      (__attribute__((address_space(3))) unsigned int*)l, 16, 0, 0);
}

// Load 8 consecutive f32 along K from a row-major matrix, convert to bf16.
static __device__ __forceinline__ bf16x8 load_a_frag_nc(const float* __restrict__ A,
                                                        int row, int k0) {
  const f32x4* p = (const f32x4*)(A + (size_t)row * D + k0);
  f32x4 v0 = p[0], v1 = p[1];
  bf16x8 r;
  r[0] = (__bf16)v0[0]; r[1] = (__bf16)v0[1]; r[2] = (__bf16)v0[2]; r[3] = (__bf16)v0[3];
  r[4] = (__bf16)v1[0]; r[5] = (__bf16)v1[1]; r[6] = (__bf16)v1[2]; r[7] = (__bf16)v1[3];
  return r;
}

// Stage a 128-row f32 [M][128] tile into XOR-swizzled bf16 LDS (32 KB).
static __device__ __forceinline__ void stage_a_tile128(const float* __restrict__ A, int M,
                                                       int row_base, char* lds, int tid) {
  const int l32 = tid & 31;
  const int g = tid >> 5;
#pragma unroll
  for (int it = 0; it < 16; ++it) {
    int rl = it * 8 + g;
    int r = row_base + rl;
    f32x4 v = {};
    if (r < M) v = *(const f32x4*)(A + (size_t)r * D + l32 * 4);
    bf16x4 b;
    b[0] = (__bf16)v[0]; b[1] = (__bf16)v[1]; b[2] = (__bf16)v[2]; b[3] = (__bf16)v[3];
    int byte = (rl * 256 + l32 * 8) ^ ((rl & 7) << 4);
    *(bf16x4*)(lds + byte) = b;
  }
}

// Read a bf16x8 A-fragment (row rl, k-offset k0) from a swizzled tile.
static __device__ __forceinline__ bf16x8 read_a_frag(const char* lds, int rl, int k0) {
  int byte = (rl * 256 + k0 * 2) ^ ((rl & 7) << 4);
  return *(const bf16x8*)(lds + byte);
}

// DPP add: x + dpp_perm(x). VALU-pipe cross-lane (no LDS latency).
template <int CTRL>
static __device__ __forceinline__ float dpp_add(float x) {
  int v = __builtin_amdgcn_update_dpp(0, __float_as_int(x), CTRL, 0xf, 0xf, true);
  return x + __int_as_float(v);
}

// Sum across each 32-lane half; result in ALL lanes of the half.
static __device__ __forceinline__ float red32(float x) {
  x = dpp_add<0xB1>(x);    // quad xor1
  x = dpp_add<0x4E>(x);    // quad xor2
  x = dpp_add<0x124>(x);   // row_ror:4
  x = dpp_add<0x128>(x);   // row_ror:8
  return x + __shfl_xor(x, 16, 64);
}

// ---- merged prep: 8 weight transposes + segment offsets, one launch ------
struct PrepArgs {
  const float* W[8];
  __bf16* WT[8];
  const int* dst;
  int* offs;
};

__global__ void prep_all(PrepArgs pa) {
  int b = blockIdx.x;
  if (b < 512) {
    int w = b >> 6;
    int t = (b & 63) * 256 + threadIdx.x;  // 16384 per weight
    int n = t & 127, k = t >> 7;
    pa.WT[w][n * 128 + k] = (__bf16)pa.W[w][k * 128 + n];
  } else {
    int n = (b - 512) * 256 + threadIdx.x;
    if (n > NN) return;
    int lo = 0, hi = NE;
    while (lo < hi) {
      int mid = (lo + hi) >> 1;
      if (pa.dst[mid] < n) lo = mid + 1; else hi = mid;
    }
    pa.offs[n] = lo;
  }
}

// ---- batched C[M,128] = A[M,128] @ B_i[128,128] for 5 weights ------------
// Round-0 structure: grid (M/128, 5), 128-row A tile, 4x4 acc per wave.
// mode: 0 = f32 row, 1 = bf16 row, 2 = KV row K-half, 3 = KV row V-half.
struct GemmBatch {
  const __bf16* BT[5];
  void* C[5];
  const float* bias[5];  // nullptr = none
  int mode[5];
};

__global__ __launch_bounds__(256) void gemm_k128_b(const float* __restrict__ A,
                                                   GemmBatch gb, int M) {
  __shared__ __align__(16) char atile[128 * 256];
  const int y = blockIdx.y;
  const __bf16* __restrict__ BT = gb.BT[y];
  const int tid = threadIdx.x;
  const int lane = tid & 63;
  const int wave = tid >> 6;
  const int wr = wave >> 1, wc = wave & 1;
  const int row0 = blockIdx.x * 128;
  const int col0 = wc * 64;
  const int lr = lane & 15;
  const int lk = (lane >> 4) << 3;

  stage_a_tile128(A, M, row0, atile, tid);
  __syncthreads();

  f32x4 acc[4][4] = {};
#pragma unroll
  for (int kk = 0; kk < 4; ++kk) {
    const int k0 = kk * 32 + lk;
    bf16x8 a[4], b[4];
#pragma unroll
    for (int m = 0; m < 4; ++m) a[m] = read_a_frag(atile, wr * 64 + m * 16 + lr, k0);
#pragma unroll
    for (int n = 0; n < 4; ++n) b[n] = *(const bf16x8*)(BT + (size_t)(col0 + n * 16 + lr) * D + k0);
#pragma unroll
    for (int m = 0; m < 4; ++m)
#pragma unroll
      for (int n = 0; n < 4; ++n)
        acc[m][n] = __builtin_amdgcn_mfma_f32_16x16x32_bf16(a[m], b[n], acc[m][n], 0, 0, 0);
  }
  const int rr = (lane >> 4) * 4;
  float bv[4] = {0.f, 0.f, 0.f, 0.f};
  if (gb.bias[y]) {
#pragma unroll
    for (int n = 0; n < 4; ++n) bv[n] = gb.bias[y][col0 + n * 16 + lr];
  }
  const int mode = gb.mode[y];
#pragma unroll
  for (int m = 0; m < 4; ++m)
#pragma unroll
    for (int j = 0; j < 4; ++j) {
      const int r = row0 + wr * 64 + m * 16 + rr + j;
      if (r < M) {
#pragma unroll
        for (int n = 0; n < 4; ++n) {
          const int c = col0 + n * 16 + lr;
          const float val = acc[m][n][j] + bv[n];
          if (mode == 0) {
            ((float*)gb.C[y])[(size_t)r * D + c] = val;
          } else if (mode == 1) {
            ((__bf16*)gb.C[y])[(size_t)r * D + c] = (__bf16)val;
          } else if (mode == 2) {
            ((__bf16*)gb.C[y])[(size_t)r * 256 + c] = (__bf16)val;       // K half
          } else {
            ((__bf16*)gb.C[y])[(size_t)r * 256 + 128 + c] = (__bf16)val; // V half
          }
        }
      }
    }
}

// ---- attn slice pipeline macros (static reg indexing only) ---------------
// Loads are unconditional (clamped to safe rows); compute is guarded by jj<n32.
#define ALD1(P, K, JJ)                                                       \
  do {                                                                       \
    const int jj_ = (JJ);                                                    \
    const int ok_ = jj_ < n32;                                               \
    int si_ = __shfl(sidx, jj_ & 31, 32);                                    \
    si_ = ok_ ? si_ : 0;                                                     \
    const int ej_ = ok_ ? (myS + jj_) : myS;                                 \
    kb##P[K] = *(const bf16x4*)(KV + (size_t)si_ * 256 + (l32 << 2));        \
    vb##P[K] = *(const bf16x4*)(KV + (size_t)si_ * 256 + 128 + (l32 << 2));  \
    eb##P[K] = *(const f32x4*)(edge + (size_t)ej_ * D + (l32 << 2));         \
  } while (0)

#define ALOADC(P, C)                                                         \
  do {                                                                       \
    const int c4_ = (C) * 4;                                                 \
    ALD1(P, 0, c4_ + 0); ALD1(P, 1, c4_ + 1);                                \
    ALD1(P, 2, c4_ + 2); ALD1(P, 3, c4_ + 3);                                \
  } while (0)

#define ACP1(P, K, JJ)                                                       \
  do {                                                                       \
    const int jj_ = (JJ);                                                    \
    const int ok_ = jj_ < n32;                                               \
    int dj_ = __shfl(didx, jj_ & 31, 32);                                    \
    dj_ = ok_ ? dj_ : cur;                                                   \
    if (dj_ != cur) {                                                        \
      flush();                                                               \
      cur = dj_;                                                             \
      qs = *(const f32x4*)(qlds + ((cur - n0) << 7) + (l32 << 2));           \
    }                                                                        \
    f32x4 ef_ = eb##P[K];                                                    \
    float x0_ = (float)kb##P[K][0] + ef_[0];                                 \
    float x1_ = (float)kb##P[K][1] + ef_[1];                                 \
    float x2_ = (float)kb##P[K][2] + ef_[2];                                 \
    float x3_ = (float)kb##P[K][3] + ef_[3];                                 \
    float pp_ = fmaf(qs[1], x1_, qs[0] * x0_) + fmaf(qs[3], x3_, qs[2] * x2_); \
    float w_ = ok_ ? exp2f(red32(pp_)) : 0.f;                                \
    l += w_;                                                                 \
    a[0] = fmaf(w_, (float)vb##P[K][0] + ef_[0], a[0]);                      \
    a[1] = fmaf(w_, (float)vb##P[K][1] + ef_[1], a[1]);                      \
    a[2] = fmaf(w_, (float)vb##P[K][2] + ef_[2], a[2]);                      \
    a[3] = fmaf(w_, (float)vb##P[K][3] + ef_[3], a[3]);                      \
  } while (0)

#define ACOMPC(P, C)                                                         \
  do {                                                                       \
    const int c4_ = (C) * 4;                                                 \
    ACP1(P, 0, c4_ + 0); ACP1(P, 1, c4_ + 1);                                \
    ACP1(P, 2, c4_ + 2); ACP1(P, 3, c4_ + 3);                                \
  } while (0)

// scale * log2(e): w = exp2(dot * CATT) == exp(dot / sqrt(128))
#define CATT 0.12751744612764933f

// ---- FUSED: 64-edge MLP blocks + attention(+Wo+LN) blocks, 3:2 ----------
__global__ __launch_bounds__(256) __attribute__((amdgpu_waves_per_eu(3)))
void fused_edge_attn(
    const float* __restrict__ edge,
    const __bf16* __restrict__ W1bT,
    const __bf16* __restrict__ W2T,
    const __bf16* __restrict__ P1,
    const __bf16* __restrict__ P3,
    const int* __restrict__ dst,
    const int* __restrict__ src,
    const float* __restrict__ b2,
    float* __restrict__ out_fused,
    const float* __restrict__ Q,
    const __bf16* __restrict__ KV,
    const int* __restrict__ offs,
    const __bf16* __restrict__ WoT,
    const float* __restrict__ noderep,
    const float* __restrict__ gamma,
    const float* __restrict__ beta,
    float* __restrict__ out_updated) {
  __shared__ __align__(16) char bufA[64 * 256];  // edge: P1 gather -> h1 | attn: qlds -> agg tile
  __shared__ __align__(16) char bufB[64 * 256];  // edge: P3 gather        | attn: nodeAcc -> xl f32
  const int tid = threadIdx.x;
  const int grp = blockIdx.x / 5;
  const int role = blockIdx.x % 5;

  if (role >= 2) {
    // ================= EDGE path (64-edge blocks) ========================
    const int ebi = grp * 3 + (role - 2);  // 0..9374
    const int eb = ebi * 64;
    const int lane = tid & 63;
    const int wave = tid >> 6;
    const int wr = wave >> 1, wc = wave & 1;
    const int lr = lane & 15;
    const int lk = (lane >> 4) << 3;
    const int col0 = wc * 64;

    // async gather: each wave covers rows wave*16 .. wave*16+15
    {
      const int gr = lane >> 4;
      const int slot = lane & 15;
      int di[4], sg[4];
#pragma unroll
      for (int c = 0; c < 4; ++c) {
        int rl = wave * 16 + c * 4 + gr;
        di[c] = dst[eb + rl];
        sg[c] = src[eb + rl];
      }
#pragma unroll
      for (int c = 0; c < 4; ++c) {
        int rl = wave * 16 + c * 4 + gr;
        int sb = (slot * 16) ^ ((rl & 7) << 4);
        gload_lds16((const char*)(P1 + (size_t)di[c] * D) + sb,
                    bufA + (wave * 16 + c * 4) * 256);
        gload_lds16((const char*)(P3 + (size_t)sg[c] * D) + sb,
                    bufB + (wave * 16 + c * 4) * 256);
      }
    }

    // MFMA1: acc = edge @ W1b (A-frags direct from global)
    f32x4 acc[2][4] = {};
#pragma unroll
    for (int kk = 0; kk < 4; ++kk) {
      const int k0 = kk * 32 + lk;
      bf16x8 a[2], b[4];
#pragma unroll
      for (int m = 0; m < 2; ++m) a[m] = load_a_frag_nc(edge, eb + wr * 32 + m * 16 + lr, k0);
#pragma unroll
      for (int n = 0; n < 4; ++n) b[n] = *(const bf16x8*)(W1bT + (size_t)(col0 + n * 16 + lr) * D + k0);
#pragma unroll
      for (int m = 0; m < 2; ++m)
#pragma unroll
        for (int n = 0; n < 4; ++n)
          acc[m][n] = __builtin_amdgcn_mfma_f32_16x16x32_bf16(a[m], b[n], acc[m][n], 0, 0, 0);
    }
    __syncthreads();  // drains vmcnt(0): all gathers landed

    // epilogue: h1 = relu(acc + P1g + P3g) -> bufA
    const int rr = (lane >> 4) * 4;
#pragma unroll
    for (int m = 0; m < 2; ++m) {
#pragma unroll
      for (int j = 0; j < 4; ++j) {
        int rl = wr * 32 + m * 16 + rr + j;
#pragma unroll
        for (int n = 0; n < 4; ++n) {
          int c = col0 + n * 16 + lr;
          int byte = (rl * 256 + c * 2) ^ ((rl & 7) << 4);
          float g1 = (float)*(const __bf16*)(bufA + byte);
          float g3 = (float)*(const __bf16*)(bufB + byte);
          float v = fmaxf(acc[m][n][j] + g1 + g3, 0.f);
          *(__bf16*)(bufA + byte) = (__bf16)v;
        }
      }
    }
    __syncthreads();

    // MFMA2: fused = h1 @ W2 + b2
    float b2v[4];
#pragma unroll
    for (int n = 0; n < 4; ++n) b2v[n] = b2[col0 + n * 16 + lr];
    f32x4 acc2[2][4] = {};
#pragma unroll
    for (int kk = 0; kk < 4; ++kk) {
      const int k0 = kk * 32 + lk;
      bf16x8 a[2], b[4];
#pragma unroll
      for (int m = 0; m < 2; ++m) a[m] = read_a_frag(bufA, wr * 32 + m * 16 + lr, k0);
#pragma unroll
      for (int n = 0; n < 4; ++n) b[n] = *(const bf16x8*)(W2T + (size_t)(col0 + n * 16 + lr) * D + k0);
#pragma unroll
      for (int m = 0; m < 2; ++m)
#pragma unroll
        for (int n = 0; n < 4; ++n)
          acc2[m][n] = __builtin_amdgcn_mfma_f32_16x16x32_bf16(a[m], b[n], acc2[m][n], 0, 0, 0);
    }
#pragma unroll
    for (int m = 0; m < 2; ++m)
#pragma unroll
      for (int j = 0; j < 4; ++j) {
        int rl = wr * 32 + m * 16 + rr + j;
        int e = eb + rl;
#pragma unroll
        for (int n = 0; n < 4; ++n) {
          int c = col0 + n * 16 + lr;
          out_fused[(size_t)e * D + c] = acc2[m][n][j] + b2v[n];
        }
      }
  } else {
    // ================= ATTN path: cooperative balanced slices ============
    // Block owns nodes n0..n0+7 and their CONTIGUOUS edge range (dst sorted).
    // 8 half-waves take equal slices of the range (load-balanced regardless
    // of per-node degree); per-segment partial (l, a) accumulated in regs,
    // flushed across node boundaries via LDS atomicAdd into nodeAcc.
    const int nw = tid >> 5;             // half-wave 0..7
    const int l32 = tid & 31;
    const int n0 = (grp * 2 + role) * 8; // 6250*8 = 50000
    float* qlds = (float*)bufA;          // [8][128] pre-scaled Q (dead after accum)
    float* nodeAcc = (float*)bufB;       // [8][132]: a[128], l at +128

    // stage pre-scaled Q rows + zero nodeAcc
    {
      f32x4 qv = *(const f32x4*)(Q + (size_t)(n0 + nw) * D + (l32 << 2));
      f32x4 qsc;
      qsc[0] = qv[0] * CATT; qsc[1] = qv[1] * CATT;
      qsc[2] = qv[2] * CATT; qsc[3] = qv[3] * CATT;
      *(f32x4*)(qlds + nw * 128 + (l32 << 2)) = qsc;
      for (int i = tid; i < 8 * 132; i += 256) nodeAcc[i] = 0.f;
    }
    __syncthreads();

    const int e0 = offs[n0], e1 = offs[n0 + 8];
    const int L = e1 - e0;
    const int per = (L + 7) >> 3;
    const int myS = e0 + nw * per;
    const int myE = (myS + per < e1) ? (myS + per) : e1;
    const int n = myE - myS;

    if (n > 0) {
      const int n32 = n < 32 ? n : 32;
      // coalesced vector preload of this slice's src/dst
      int sidx = 0, didx = 0;
      {
        int gi = myS + l32;
        if (l32 < n) { sidx = src[gi]; didx = dst[gi]; }
      }
      int cur = __shfl(didx, 0, 32);  // dst[myS], uniform per half-wave
      f32x4 qs = *(const f32x4*)(qlds + ((cur - n0) << 7) + (l32 << 2));
      float l = 0.f;
      f32x4 a = {0.f, 0.f, 0.f, 0.f};
      auto flush = [&]() {
        float* na = nodeAcc + (cur - n0) * 132;
        atomicAdd(na + (l32 << 2) + 0, a[0]);
        atomicAdd(na + (l32 << 2) + 1, a[1]);
        atomicAdd(na + (l32 << 2) + 2, a[2]);
        atomicAdd(na + (l32 << 2) + 3, a[3]);
        if (l32 == 0) atomicAdd(na + 128, l);
        a[0] = 0.f; a[1] = 0.f; a[2] = 0.f; a[3] = 0.f;
        l = 0.f;
      };

      bf16x4 kb0[4], vb0[4]; f32x4 eb0[4];
      bf16x4 kb1[4], vb1[4]; f32x4 eb1[4];
      const int nch = (n32 + 3) >> 2;
      ALOADC(0, 0);
      for (int c = 0; c < nch; c += 2) {
        if (c + 1 < nch) ALOADC(1, c + 1);
        ACOMPC(0, c);
        if (c + 2 < nch) ALOADC(0, c + 2);
        if (c + 1 < nch) ACOMPC(1, c + 1);
      }
      // tail for slices > 32 edges (needs L > 256: essentially impossible)
      for (int i = myS + 32; i < myE; ++i) {
        int si = src[i];
        int dj = dst[i];
        if (dj != cur) {
          flush();
          cur = dj;
          qs = *(const f32x4*)(qlds + ((cur - n0) << 7) + (l32 << 2));
        }
        bf16x4 kbx = *(const bf16x4*)(KV + (size_t)si * 256 + (l32 << 2));
        bf16x4 vbx = *(const bf16x4*)(KV + (size_t)si * 256 + 128 + (l32 << 2));
        f32x4 ef = *(const f32x4*)(edge + (size_t)i * D + (l32 << 2));
        float x0 = (float)kbx[0] + ef[0], x1 = (float)kbx[1] + ef[1];
        float x2 = (float)kbx[2] + ef[2], x3 = (float)kbx[3] + ef[3];
        float pp = fmaf(qs[1], x1, qs[0] * x0) + fmaf(qs[3], x3, qs[2] * x2);
        float w = exp2f(red32(pp));
        l += w;
        a[0] = fmaf(w, (float)vbx[0] + ef[0], a[0]);
        a[1] = fmaf(w, (float)vbx[1] + ef[1], a[1]);
        a[2] = fmaf(w, (float)vbx[2] + ef[2], a[2]);
        a[3] = fmaf(w, (float)vbx[3] + ef[3], a[3]);
      }
      flush();
    }
    __syncthreads();  // all atomics done

    // ---- normalize + agg row -> swizzled bf16 LDS (row nw of A tile) ----
    {
      float lsum = nodeAcc[nw * 132 + 128];
      f32x4 av = *(const f32x4*)(nodeAcc + nw * 132 + (l32 << 2));
      float inv = lsum > 0.f ? 1.f / lsum : 0.f;
      bf16x4 rb;
      rb[0] = (__bf16)(av[0] * inv); rb[1] = (__bf16)(av[1] * inv);
      rb[2] = (__bf16)(av[2] * inv); rb[3] = (__bf16)(av[3] * inv);
      int byte = (nw * 256 + l32 * 8) ^ ((nw & 7) << 4);
      *(bf16x4*)(bufA + byte) = rb;  // overwrites qlds (dead)
    }
    __syncthreads();

    // ---- Wo GEMM: rows 0..7 of aggTile @ Wo; cols split 2 n-tiles/wave ---
    {
      const int wave = tid >> 6;
      const int lane = tid & 63;
      const int lr = lane & 15;
      const int lk = (lane >> 4) << 3;
      f32x4 acc[2] = {};
#pragma unroll
      for (int kk = 0; kk < 4; ++kk) {
        int k0 = kk * 32 + lk;
        bf16x8 af = read_a_frag(bufA, lr, k0);
#pragma unroll
        for (int t = 0; t < 2; ++t) {
          int nn = wave * 2 + t;
          bf16x8 b = *(const bf16x8*)(WoT + (size_t)(nn * 16 + lr) * D + k0);
          acc[t] = __builtin_amdgcn_mfma_f32_16x16x32_bf16(af, b, acc[t], 0, 0, 0);
        }
      }
      float* xl = (float*)bufB;  // [8][128], overwrites nodeAcc (dead)
      const int rr = (lane >> 4) * 4;
      if (rr < 8) {
#pragma unroll
        for (int t = 0; t < 2; ++t) {
          int nn = wave * 2 + t;
#pragma unroll
          for (int j = 0; j < 4; ++j)
            xl[(rr + j) * 128 + nn * 16 + lr] = acc[t][j];
        }
      }
    }
    __syncthreads();

    // ---- LN per half-wave: updated = LN(node + aggWo) --------------------
    {
      const int node = n0 + nw;
      const float* xl = (const float*)bufB;
      f32x4 xv = *(const f32x4*)(xl + nw * 128 + l32 * 4);
      f32x4 nv = *(const f32x4*)(noderep + (size_t)node * D + l32 * 4);
      float x0 = xv[0] + nv[0], x1 = xv[1] + nv[1];
      float x2 = xv[2] + nv[2], x3 = xv[3] + nv[3];
      float s = red32(x0 + x1 + x2 + x3);
      float mu = s * (1.f / 128.f);
      float d0 = x0 - mu, d1 = x1 - mu, d2 = x2 - mu, d3 = x3 - mu;
      float vv = red32(d0 * d0 + d1 * d1 + d2 * d2 + d3 * d3);
      float rstd = rsqrtf(vv * (1.f / 128.f) + 1e-5f);
      f32x4 g = *(const f32x4*)(gamma + l32 * 4);
      f32x4 bb = *(const f32x4*)(beta + l32 * 4);
      f32x4 o;
      o[0] = d0 * rstd * g[0] + bb[0];
      o[1] = d1 * rstd * g[1] + bb[1];
      o[2] = d2 * rstd * g[2] + bb[2];
      o[3] = d3 * rstd * g[3] + bb[3];
      *(f32x4*)(out_updated + (size_t)node * D + l32 * 4) = o;
    }
  }
}

// ---- launch ---------------------------------------------------------------
extern "C" void kernel_launch(void* const* d_in, const int* in_sizes, int n_in,
                              void* d_out, int out_size, void* d_ws, size_t ws_size,
                              hipStream_t stream) {
  const float* node = (const float*)d_in[0];
  const float* edge = (const float*)d_in[1];
  const int* src = (const int*)d_in[2];
  const int* dst = (const int*)d_in[3];
  const float* Wq = (const float*)d_in[4];
  const float* Wk = (const float*)d_in[5];
  const float* Wv = (const float*)d_in[6];
  const float* Wo = (const float*)d_in[7];
  const float* gamma = (const float*)d_in[8];
  const float* beta = (const float*)d_in[9];
  const float* W1 = (const float*)d_in[10];
  const float* b1 = (const float*)d_in[11];
  const float* W2 = (const float*)d_in[12];
  const float* b2 = (const float*)d_in[13];

  float* out_updated = (float*)d_out;
  float* out_fused = (float*)d_out + (size_t)NN * D;

  char* ws = (char*)d_ws;
  size_t o = 0;
  auto take = [&](size_t bytes) {
    char* p = ws + o;
    o = (o + bytes + 255) & ~(size_t)255;
    return p;
  };
  int* offs = (int*)take((NN + 1) * sizeof(int));
  __bf16* WqT = (__bf16*)take(128 * 128 * 2);
  __bf16* WkT = (__bf16*)take(128 * 128 * 2);
  __bf16* WvT = (__bf16*)take(128 * 128 * 2);
  __bf16* WoT = (__bf16*)take(128 * 128 * 2);
  __bf16* W1aT = (__bf16*)take(128 * 128 * 2);
  __bf16* W1bT = (__bf16*)take(128 * 128 * 2);
  __bf16* W1cT = (__bf16*)take(128 * 128 * 2);
  __bf16* W2T = (__bf16*)take(128 * 128 * 2);
  float* Qb = (float*)take((size_t)NN * D * 4);
  __bf16* KVb = (__bf16*)take((size_t)NN * 256 * 2);  // [K(128) | V(128)] per node
  __bf16* P1b = (__bf16*)take((size_t)NN * D * 2);
  __bf16* P3b = (__bf16*)take((size_t)NN * D * 2);

  PrepArgs pa;
  pa.W[0] = Wq; pa.WT[0] = WqT;
  pa.W[1] = Wk; pa.WT[1] = WkT;
  pa.W[2] = Wv; pa.WT[2] = WvT;
  pa.W[3] = Wo; pa.WT[3] = WoT;
  pa.W[4] = W1; pa.WT[4] = W1aT;
  pa.W[5] = W1 + 128 * 128; pa.WT[5] = W1bT;
  pa.W[6] = W1 + 256 * 128; pa.WT[6] = W1cT;
  pa.W[7] = W2; pa.WT[7] = W2T;
  pa.dst = dst; pa.offs = offs;
  prep_all<<<512 + (NN + 256) / 256, 256, 0, stream>>>(pa);

  int gnode = (NN + 127) / 128;
  GemmBatch gb;
  gb.BT[0] = WqT;  gb.C[0] = Qb;  gb.bias[0] = nullptr; gb.mode[0] = 0;
  gb.BT[1] = WkT;  gb.C[1] = KVb; gb.bias[1] = nullptr; gb.mode[1] = 2;
  gb.BT[2] = WvT;  gb.C[2] = KVb; gb.bias[2] = nullptr; gb.mode[2] = 3;
  gb.BT[3] = W1aT; gb.C[3] = P1b; gb.bias[3] = b1;      gb.mode[3] = 1;
  gb.BT[4] = W1cT; gb.C[4] = P3b; gb.bias[4] = nullptr; gb.mode[4] = 1;
  gemm_k128_b<<<dim3(gnode, 5), 256, 0, stream>>>(node, gb, NN);

  // fused: 6250 attn(+Wo+LN) blocks + 9375 64-edge blocks, 2:3 per group of 5
  fused_edge_attn<<<15625, 256, 0, stream>>>(edge, W1bT, W2T, P1b, P3b, dst, src,
                                             b2, out_fused, Qb, KVb, offs,
                                             WoT, node, gamma, beta, out_updated);
}

// Round 5
// 426.884 us; speedup vs baseline: 1.0254x; 1.0254x over previous
//
#include <hip/hip_runtime.h>
#include <hip/hip_bf16.h>

#define NN 50000
#define NE 600000
#define D 128

typedef __bf16 bf16x8 __attribute__((ext_vector_type(8)));
typedef __bf16 bf16x4 __attribute__((ext_vector_type(4)));
typedef float f32x4 __attribute__((ext_vector_type(4)));

// ---- helpers -------------------------------------------------------------

// Load 8 consecutive f32 along K from a row-major matrix, convert to bf16.
static __device__ __forceinline__ bf16x8 load_a_frag_nc(const float* __restrict__ A,
                                                        int row, int k0) {
  const f32x4* p = (const f32x4*)(A + (size_t)row * D + k0);
  f32x4 v0 = p[0], v1 = p[1];
  bf16x8 r;
  r[0] = (__bf16)v0[0]; r[1] = (__bf16)v0[1]; r[2] = (__bf16)v0[2]; r[3] = (__bf16)v0[3];
  r[4] = (__bf16)v1[0]; r[5] = (__bf16)v1[1]; r[6] = (__bf16)v1[2]; r[7] = (__bf16)v1[3];
  return r;
}

// Stage a 128-row f32 [M][128] tile into XOR-swizzled bf16 LDS (32 KB).
static __device__ __forceinline__ void stage_a_tile128(const float* __restrict__ A, int M,
                                                       int row_base, char* lds, int tid) {
  const int l32 = tid & 31;
  const int g = tid >> 5;
#pragma unroll
  for (int it = 0; it < 16; ++it) {
    int rl = it * 8 + g;
    int r = row_base + rl;
    f32x4 v = {};
    if (r < M) v = *(const f32x4*)(A + (size_t)r * D + l32 * 4);
    bf16x4 b;
    b[0] = (__bf16)v[0]; b[1] = (__bf16)v[1]; b[2] = (__bf16)v[2]; b[3] = (__bf16)v[3];
    int byte = (rl * 256 + l32 * 8) ^ ((rl & 7) << 4);
    *(bf16x4*)(lds + byte) = b;
  }
}

// Read a bf16x8 A-fragment (row rl, k-offset k0) from a swizzled tile.
static __device__ __forceinline__ bf16x8 read_a_frag(const char* lds, int rl, int k0) {
  int byte = (rl * 256 + k0 * 2) ^ ((rl & 7) << 4);
  return *(const bf16x8*)(lds + byte);
}

// DPP add: x + dpp_perm(x). VALU-pipe cross-lane (no LDS latency).
template <int CTRL>
static __device__ __forceinline__ float dpp_add(float x) {
  int v = __builtin_amdgcn_update_dpp(0, __float_as_int(x), CTRL, 0xf, 0xf, true);
  return x + __int_as_float(v);
}

// Sum across each 32-lane half; result in ALL lanes of the half.
static __device__ __forceinline__ float red32(float x) {
  x = dpp_add<0xB1>(x);    // quad xor1
  x = dpp_add<0x4E>(x);    // quad xor2
  x = dpp_add<0x124>(x);   // row_ror:4
  x = dpp_add<0x128>(x);   // row_ror:8
  return x + __shfl_xor(x, 16, 64);
}

// ---- merged prep: 8 weight transposes + segment offsets, one launch ------
struct PrepArgs {
  const float* W[8];
  __bf16* WT[8];
  const int* dst;
  int* offs;
};

__global__ void prep_all(PrepArgs pa) {
  int b = blockIdx.x;
  if (b < 512) {
    int w = b >> 6;
    int t = (b & 63) * 256 + threadIdx.x;  // 16384 per weight
    int n = t & 127, k = t >> 7;
    pa.WT[w][n * 128 + k] = (__bf16)pa.W[w][k * 128 + n];
  } else {
    int n = (b - 512) * 256 + threadIdx.x;
    if (n > NN) return;
    int lo = 0, hi = NE;
    while (lo < hi) {
      int mid = (lo + hi) >> 1;
      if (pa.dst[mid] < n) lo = mid + 1; else hi = mid;
    }
    pa.offs[n] = lo;
  }
}

// ---- batched C[M,128] = A[M,128] @ B_i[128,128] for 5 weights ------------
// mode: 0 = f32 row, 1 = bf16 row, 2 = KV row K-half, 3 = KV row V-half.
struct GemmBatch {
  const __bf16* BT[5];
  void* C[5];
  const float* bias[5];  // nullptr = none
  int mode[5];
};

__global__ __launch_bounds__(256) void gemm_k128_b(const float* __restrict__ A,
                                                   GemmBatch gb, int M) {
  __shared__ __align__(16) char atile[128 * 256];
  const int y = blockIdx.y;
  const __bf16* __restrict__ BT = gb.BT[y];
  const int tid = threadIdx.x;
  const int lane = tid & 63;
  const int wave = tid >> 6;
  const int wr = wave >> 1, wc = wave & 1;
  const int row0 = blockIdx.x * 128;
  const int col0 = wc * 64;
  const int lr = lane & 15;
  const int lk = (lane >> 4) << 3;

  stage_a_tile128(A, M, row0, atile, tid);
  __syncthreads();

  f32x4 acc[4][4] = {};
#pragma unroll
  for (int kk = 0; kk < 4; ++kk) {
    const int k0 = kk * 32 + lk;
    bf16x8 a[4], b[4];
#pragma unroll
    for (int m = 0; m < 4; ++m) a[m] = read_a_frag(atile, wr * 64 + m * 16 + lr, k0);
#pragma unroll
    for (int n = 0; n < 4; ++n) b[n] = *(const bf16x8*)(BT + (size_t)(col0 + n * 16 + lr) * D + k0);
#pragma unroll
    for (int m = 0; m < 4; ++m)
#pragma unroll
      for (int n = 0; n < 4; ++n)
        acc[m][n] = __builtin_amdgcn_mfma_f32_16x16x32_bf16(a[m], b[n], acc[m][n], 0, 0, 0);
  }
  const int rr = (lane >> 4) * 4;
  float bv[4] = {0.f, 0.f, 0.f, 0.f};
  if (gb.bias[y]) {
#pragma unroll
    for (int n = 0; n < 4; ++n) bv[n] = gb.bias[y][col0 + n * 16 + lr];
  }
  const int mode = gb.mode[y];
#pragma unroll
  for (int m = 0; m < 4; ++m)
#pragma unroll
    for (int j = 0; j < 4; ++j) {
      const int r = row0 + wr * 64 + m * 16 + rr + j;
      if (r < M) {
#pragma unroll
        for (int n = 0; n < 4; ++n) {
          const int c = col0 + n * 16 + lr;
          const float val = acc[m][n][j] + bv[n];
          if (mode == 0) {
            ((float*)gb.C[y])[(size_t)r * D + c] = val;
          } else if (mode == 1) {
            ((__bf16*)gb.C[y])[(size_t)r * D + c] = (__bf16)val;
          } else if (mode == 2) {
            ((__bf16*)gb.C[y])[(size_t)r * 256 + c] = (__bf16)val;       // K half
          } else {
            ((__bf16*)gb.C[y])[(size_t)r * 256 + 128 + c] = (__bf16)val; // V half
          }
        }
      }
    }
}

// ---- attn chunk pipeline macros (static reg indexing only; R3 proven) ----
#define LD1(P, K, J, SV)                                                     \
  do {                                                                       \
    const int jj_ = (J);                                                     \
    const int jc_ = jj_ < jm ? jj_ : 0;                                      \
    int si_ = __shfl((SV), jj_ & 31, 32);                                    \
    si_ = jj_ < jm ? si_ : 0;                                                \
    kb##P[K] = *(const bf16x4*)(KV + (size_t)si_ * 256 + (l32 << 2));        \
    vb##P[K] = *(const bf16x4*)(KV + (size_t)si_ * 256 + 128 + (l32 << 2));  \
    eb##P[K] = *(const f32x4*)(edge + (size_t)(s0 + jc_) * D + (l32 << 2));  \
  } while (0)

#define LOADC(P, C)                                                          \
  do {                                                                       \
    const int c4_ = (C) * 4;                                                 \
    const int sv_ = (c4_ < 32) ? sidx0 : sidx1;                              \
    LD1(P, 0, c4_ + 0, sv_); LD1(P, 1, c4_ + 1, sv_);                        \
    LD1(P, 2, c4_ + 2, sv_); LD1(P, 3, c4_ + 3, sv_);                        \
  } while (0)

#define CP1(P, K, J)                                                         \
  do {                                                                       \
    const int jj_ = (J);                                                     \
    f32x4 ef_ = eb##P[K];                                                    \
    float x0_ = (float)kb##P[K][0] + ef_[0];                                 \
    float x1_ = (float)kb##P[K][1] + ef_[1];                                 \
    float x2_ = (float)kb##P[K][2] + ef_[2];                                 \
    float x3_ = (float)kb##P[K][3] + ef_[3];                                 \
    float pp_ = fmaf(qs[1], x1_, qs[0] * x0_) + fmaf(qs[3], x3_, qs[2] * x2_); \
    float s_ = red32(pp_);                                                   \
    float w_ = jj_ < jm ? exp2f(s_) : 0.f;                                   \
    l += w_;                                                                 \
    a[0] = fmaf(w_, (float)vb##P[K][0] + ef_[0], a[0]);                      \
    a[1] = fmaf(w_, (float)vb##P[K][1] + ef_[1], a[1]);                      \
    a[2] = fmaf(w_, (float)vb##P[K][2] + ef_[2], a[2]);                      \
    a[3] = fmaf(w_, (float)vb##P[K][3] + ef_[3], a[3]);                      \
  } while (0)

#define COMPC(P, C)                                                          \
  do {                                                                       \
    const int cc4_ = (C) * 4;                                                \
    CP1(P, 0, cc4_ + 0); CP1(P, 1, cc4_ + 1);                                \
    CP1(P, 2, cc4_ + 2); CP1(P, 3, cc4_ + 3);                                \
  } while (0)

// ---- FUSED: 64-edge MLP blocks + attention(+Wo+LN) blocks ----------------
// 16 KB LDS/block (edge path gathers P1/P3 into REGISTERS in the epilogue
// instead of LDS staging) -> LDS block ceiling 10/CU; VGPR capped 128.
// XCD affinity: group's 5 blocks share blockIdx%8 -> same XCD L2 sees the
// group's aligned edge range twice (attn bias read + MLP A-frags).
__global__ __launch_bounds__(256) __attribute__((amdgpu_waves_per_eu(4)))
void fused_edge_attn(
    const float* __restrict__ edge,
    const __bf16* __restrict__ W1bT,
    const __bf16* __restrict__ W2T,
    const __bf16* __restrict__ P1,
    const __bf16* __restrict__ P3,
    const int* __restrict__ dst,
    const int* __restrict__ src,
    const float* __restrict__ b2,
    float* __restrict__ out_fused,
    const float* __restrict__ Q,
    const __bf16* __restrict__ KV,
    const int* __restrict__ offs,
    const __bf16* __restrict__ WoT,
    const float* __restrict__ noderep,
    const float* __restrict__ gamma,
    const float* __restrict__ beta,
    float* __restrict__ out_updated) {
  __shared__ __align__(16) char buf[64 * 256];  // 16 KB: edge h1 | attn agg + xl
  const int tid = threadIdx.x;
  // XCD-affine decode: blockIdx%8 == group%8 for all 5 roles of a group.
  const int b = blockIdx.x;
  const int x = b & 7;
  const int t = b >> 3;          // 0..1954
  const int grp = (t / 5) * 8 + x;
  const int role = t % 5;
  if (grp >= 3125) return;

  if (role >= 2) {
    // ================= EDGE path (64-edge blocks, reg-gather epilogue) ===
    const int ebi = grp * 3 + (role - 2);  // 0..9374
    const int eb = ebi * 64;
    const int lane = tid & 63;
    const int wave = tid >> 6;
    const int wr = wave >> 1, wc = wave & 1;
    const int lr = lane & 15;
    const int lk = (lane >> 4) << 3;
    const int col0 = wc * 64;
    const int rr = (lane >> 4) * 4;

    // MFMA1: acc = edge @ W1b (A-frags direct from global)
    f32x4 acc[2][4] = {};
#pragma unroll
    for (int kk = 0; kk < 4; ++kk) {
      const int k0 = kk * 32 + lk;
      bf16x8 a[2], bm[4];
#pragma unroll
      for (int m = 0; m < 2; ++m) a[m] = load_a_frag_nc(edge, eb + wr * 32 + m * 16 + lr, k0);
#pragma unroll
      for (int n = 0; n < 4; ++n) bm[n] = *(const bf16x8*)(W1bT + (size_t)(col0 + n * 16 + lr) * D + k0);
#pragma unroll
      for (int m = 0; m < 2; ++m)
#pragma unroll
        for (int n = 0; n < 4; ++n)
          acc[m][n] = __builtin_amdgcn_mfma_f32_16x16x32_bf16(a[m], bm[n], acc[m][n], 0, 0, 0);
    }

    // epilogue: h1 = relu(acc + P1[dst] + P3[src]) -> buf (swizzled bf16).
    // g1/g3 gathered straight to registers; each 16-lane group reads 32 B
    // contiguous of an L2-resident table row.
#pragma unroll
    for (int m = 0; m < 2; ++m) {
#pragma unroll
      for (int j = 0; j < 4; ++j) {
        const int rl = wr * 32 + m * 16 + rr + j;
        const __bf16* __restrict__ p1r = P1 + (size_t)dst[eb + rl] * D;
        const __bf16* __restrict__ p3r = P3 + (size_t)src[eb + rl] * D;
#pragma unroll
        for (int n = 0; n < 4; ++n) {
          const int c = col0 + n * 16 + lr;
          float v = fmaxf(acc[m][n][j] + (float)p1r[c] + (float)p3r[c], 0.f);
          int byte = (rl * 256 + c * 2) ^ ((rl & 7) << 4);
          *(__bf16*)(buf + byte) = (__bf16)v;
        }
      }
    }
    __syncthreads();

    // MFMA2: fused = h1 @ W2 + b2
    float b2v[4];
#pragma unroll
    for (int n = 0; n < 4; ++n) b2v[n] = b2[col0 + n * 16 + lr];
    f32x4 acc2[2][4] = {};
#pragma unroll
    for (int kk = 0; kk < 4; ++kk) {
      const int k0 = kk * 32 + lk;
      bf16x8 a[2], bm[4];
#pragma unroll
      for (int m = 0; m < 2; ++m) a[m] = read_a_frag(buf, wr * 32 + m * 16 + lr, k0);
#pragma unroll
      for (int n = 0; n < 4; ++n) bm[n] = *(const bf16x8*)(W2T + (size_t)(col0 + n * 16 + lr) * D + k0);
#pragma unroll
      for (int m = 0; m < 2; ++m)
#pragma unroll
        for (int n = 0; n < 4; ++n)
          acc2[m][n] = __builtin_amdgcn_mfma_f32_16x16x32_bf16(a[m], bm[n], acc2[m][n], 0, 0, 0);
    }
#pragma unroll
    for (int m = 0; m < 2; ++m)
#pragma unroll
      for (int j = 0; j < 4; ++j) {
        int rl = wr * 32 + m * 16 + rr + j;
        int e = eb + rl;
#pragma unroll
        for (int n = 0; n < 4; ++n) {
          int c = col0 + n * 16 + lr;
          out_fused[(size_t)e * D + c] = acc2[m][n][j] + b2v[n];
        }
      }
  } else {
    // ================= ATTN path (R3 per-node chunk pipeline) ============
    const int nw = tid >> 5;                  // node-slot 0..7 (32-lane halves)
    const int node = (grp * 2 + role) * 8 + nw;  // 6250*8 = 50000
    const int l32 = tid & 31;
    int s0 = offs[node], s1 = offs[node + 1];
    int cnt = s1 - s0;
    f32x4 q = *(const f32x4*)(Q + (size_t)node * D + l32 * 4);
    // fold 1/sqrt(128) * log2(e) into q; use exp2
    f32x4 qs;
    qs[0] = q[0] * 0.12751744612764933f; qs[1] = q[1] * 0.12751744612764933f;
    qs[2] = q[2] * 0.12751744612764933f; qs[3] = q[3] * 0.12751744612764933f;
    float l = 0.f;
    f32x4 a = {0.f, 0.f, 0.f, 0.f};

    const int jm = cnt < 64 ? cnt : 64;
    if (jm > 0) {
      // contiguous src indices: coalesced vector preload
      int sidx0 = 0, sidx1 = 0;
      if (l32 < cnt) sidx0 = src[s0 + l32];
      if (l32 + 32 < cnt) sidx1 = src[s0 + 32 + l32];
      bf16x4 kb0[4], vb0[4]; f32x4 eb0[4];
      bf16x4 kb1[4], vb1[4]; f32x4 eb1[4];
      const int nch = (jm + 3) >> 2;
      LOADC(0, 0);
      for (int c = 0; c < nch; c += 2) {
        if (c + 1 < nch) LOADC(1, c + 1);
        COMPC(0, c);
        if (c + 2 < nch) LOADC(0, c + 2);
        if (c + 1 < nch) COMPC(1, c + 1);
      }
      // remainder (cnt > 64): statistically never taken
      for (int i = 64; i < cnt; ++i) {
        int si = src[s0 + i];
        bf16x4 kbx = *(const bf16x4*)(KV + (size_t)si * 256 + (l32 << 2));
        bf16x4 vbx = *(const bf16x4*)(KV + (size_t)si * 256 + 128 + (l32 << 2));
        f32x4 ef = *(const f32x4*)(edge + (size_t)(s0 + i) * D + (l32 << 2));
        float x0 = (float)kbx[0] + ef[0], x1 = (float)kbx[1] + ef[1];
        float x2 = (float)kbx[2] + ef[2], x3 = (float)kbx[3] + ef[3];
        float pp = fmaf(qs[1], x1, qs[0] * x0) + fmaf(qs[3], x3, qs[2] * x2);
        float w = exp2f(red32(pp));
        l += w;
        a[0] = fmaf(w, (float)vbx[0] + ef[0], a[0]);
        a[1] = fmaf(w, (float)vbx[1] + ef[1], a[1]);
        a[2] = fmaf(w, (float)vbx[2] + ef[2], a[2]);
        a[3] = fmaf(w, (float)vbx[3] + ef[3], a[3]);
      }
    }
    float inv = l > 0.f ? 1.f / l : 0.f;
    f32x4 r;
    r[0] = a[0] * inv; r[1] = a[1] * inv; r[2] = a[2] * inv; r[3] = a[3] * inv;

    // ---- agg row -> swizzled bf16 LDS (row nw of a 16-row A tile) --------
    {
      bf16x4 rb;
      rb[0] = (__bf16)r[0]; rb[1] = (__bf16)r[1];
      rb[2] = (__bf16)r[2]; rb[3] = (__bf16)r[3];
      int byte = (nw * 256 + l32 * 8) ^ ((nw & 7) << 4);
      *(bf16x4*)(buf + byte) = rb;
    }
    __syncthreads();

    // ---- Wo GEMM: rows 0..7 of aggTile @ Wo; cols split 2 n-tiles/wave ---
    // Rows 8..15 of the A tile are stale; MFMA output row r depends only on
    // A row r, so rows 0..7 of the product are exact.
    {
      const int wave = tid >> 6;
      const int lane = tid & 63;
      const int lr = lane & 15;
      const int lk = (lane >> 4) << 3;
      f32x4 acc[2] = {};
#pragma unroll
      for (int kk = 0; kk < 4; ++kk) {
        int k0 = kk * 32 + lk;
        bf16x8 af = read_a_frag(buf, lr, k0);
#pragma unroll
        for (int tt = 0; tt < 2; ++tt) {
          int nn = wave * 2 + tt;
          bf16x8 bm = *(const bf16x8*)(WoT + (size_t)(nn * 16 + lr) * D + k0);
          acc[tt] = __builtin_amdgcn_mfma_f32_16x16x32_bf16(af, bm, acc[tt], 0, 0, 0);
        }
      }
      float* xl = (float*)(buf + 8192);  // [8][128]
      const int rr = (lane >> 4) * 4;
      if (rr < 8) {
#pragma unroll
        for (int tt = 0; tt < 2; ++tt) {
          int nn = wave * 2 + tt;
#pragma unroll
          for (int j = 0; j < 4; ++j)
            xl[(rr + j) * 128 + nn * 16 + lr] = acc[tt][j];
        }
      }
    }
    __syncthreads();

    // ---- LN per node-slot: updated = LN(node + aggWo) --------------------
    {
      const float* xl = (const float*)(buf + 8192);
      f32x4 xv = *(const f32x4*)(xl + nw * 128 + l32 * 4);
      f32x4 nv = *(const f32x4*)(noderep + (size_t)node * D + l32 * 4);
      float x0 = xv[0] + nv[0], x1 = xv[1] + nv[1];
      float x2 = xv[2] + nv[2], x3 = xv[3] + nv[3];
      float s = red32(x0 + x1 + x2 + x3);
      float mu = s * (1.f / 128.f);
      float d0 = x0 - mu, d1 = x1 - mu, d2 = x2 - mu, d3 = x3 - mu;
      float vv = red32(d0 * d0 + d1 * d1 + d2 * d2 + d3 * d3);
      float rstd = rsqrtf(vv * (1.f / 128.f) + 1e-5f);
      f32x4 g = *(const f32x4*)(gamma + l32 * 4);
      f32x4 bb = *(const f32x4*)(beta + l32 * 4);
      f32x4 o;
      o[0] = d0 * rstd * g[0] + bb[0];
      o[1] = d1 * rstd * g[1] + bb[1];
      o[2] = d2 * rstd * g[2] + bb[2];
      o[3] = d3 * rstd * g[3] + bb[3];
      *(f32x4*)(out_updated + (size_t)node * D + l32 * 4) = o;
    }
  }
}

// ---- launch ---------------------------------------------------------------
extern "C" void kernel_launch(void* const* d_in, const int* in_sizes, int n_in,
                              void* d_out, int out_size, void* d_ws, size_t ws_size,
                              hipStream_t stream) {
  const float* node = (const float*)d_in[0];
  const float* edge = (const float*)d_in[1];
  const int* src = (const int*)d_in[2];
  const int* dst = (const int*)d_in[3];
  const float* Wq = (const float*)d_in[4];
  const float* Wk = (const float*)d_in[5];
  const float* Wv = (const float*)d_in[6];
  const float* Wo = (const float*)d_in[7];
  const float* gamma = (const float*)d_in[8];
  const float* beta = (const float*)d_in[9];
  const float* W1 = (const float*)d_in[10];
  const float* b1 = (const float*)d_in[11];
  const float* W2 = (const float*)d_in[12];
  const float* b2 = (const float*)d_in[13];

  float* out_updated = (float*)d_out;
  float* out_fused = (float*)d_out + (size_t)NN * D;

  char* ws = (char*)d_ws;
  size_t o = 0;
  auto take = [&](size_t bytes) {
    char* p = ws + o;
    o = (o + bytes + 255) & ~(size_t)255;
    return p;
  };
  int* offs = (int*)take((NN + 1) * sizeof(int));
  __bf16* WqT = (__bf16*)take(128 * 128 * 2);
  __bf16* WkT = (__bf16*)take(128 * 128 * 2);
  __bf16* WvT = (__bf16*)take(128 * 128 * 2);
  __bf16* WoT = (__bf16*)take(128 * 128 * 2);
  __bf16* W1aT = (__bf16*)take(128 * 128 * 2);
  __bf16* W1bT = (__bf16*)take(128 * 128 * 2);
  __bf16* W1cT = (__bf16*)take(128 * 128 * 2);
  __bf16* W2T = (__bf16*)take(128 * 128 * 2);
  float* Qb = (float*)take((size_t)NN * D * 4);
  __bf16* KVb = (__bf16*)take((size_t)NN * 256 * 2);  // [K(128) | V(128)] per node
  __bf16* P1b = (__bf16*)take((size_t)NN * D * 2);
  __bf16* P3b = (__bf16*)take((size_t)NN * D * 2);

  PrepArgs pa;
  pa.W[0] = Wq; pa.WT[0] = WqT;
  pa.W[1] = Wk; pa.WT[1] = WkT;
  pa.W[2] = Wv; pa.WT[2] = WvT;
  pa.W[3] = Wo; pa.WT[3] = WoT;
  pa.W[4] = W1; pa.WT[4] = W1aT;
  pa.W[5] = W1 + 128 * 128; pa.WT[5] = W1bT;
  pa.W[6] = W1 + 256 * 128; pa.WT[6] = W1cT;
  pa.W[7] = W2; pa.WT[7] = W2T;
  pa.dst = dst; pa.offs = offs;
  prep_all<<<512 + (NN + 256) / 256, 256, 0, stream>>>(pa);

  int gnode = (NN + 127) / 128;
  GemmBatch gb;
  gb.BT[0] = WqT;  gb.C[0] = Qb;  gb.bias[0] = nullptr; gb.mode[0] = 0;
  gb.BT[1] = WkT;  gb.C[1] = KVb; gb.bias[1] = nullptr; gb.mode[1] = 2;
  gb.BT[2] = WvT;  gb.C[2] = KVb; gb.bias[2] = nullptr; gb.mode[2] = 3;
  gb.BT[3] = W1aT; gb.C[3] = P1b; gb.bias[3] = b1;      gb.mode[3] = 1;
  gb.BT[4] = W1cT; gb.C[4] = P3b; gb.bias[4] = nullptr; gb.mode[4] = 1;
  gemm_k128_b<<<dim3(gnode, 5), 256, 0, stream>>>(node, gb, NN);

  // fused: XCD-affine grid 8 residues x 391 slots x 5 roles (15 dead blocks)
  fused_edge_attn<<<15640, 256, 0, stream>>>(edge, W1bT, W2T, P1b, P3b, dst, src,
                                             b2, out_fused, Qb, KVb, offs,
                                             WoT, node, gamma, beta, out_updated);
}